// Round 1
// baseline (22597.923 us; speedup 1.0000x reference)
//
#include <hip/hip_runtime.h>

// LSTM: N=256, L=2048, IN=8, H1=256, H2=128, OUT=1
// d_in: 0:x [256,2048,8] 1:W_ih[1024,9] 2:W_hh[1024,256] 3:b_ih[1024] 4:b_hh[1024]
//       5:W1[128,256] 6:b1[128] 7:W2[1,128] 8:b2[1]
// d_out: output [256,2048,1] f32  then cell_states [256,2048,256] f32

typedef __attribute__((ext_vector_type(8))) short short8;
typedef __attribute__((ext_vector_type(4))) float f32x4;

#define LSEQ 2048

__device__ __forceinline__ unsigned short f2bf(float f) {
  unsigned int u = __float_as_uint(f);
  unsigned int r = (u + 0x7FFFu + ((u >> 16) & 1u)) >> 16;
  return (unsigned short)r;
}
__device__ __forceinline__ float bf2f(unsigned short b) {
  return __uint_as_float(((unsigned int)b) << 16);
}
__device__ __forceinline__ float sigm(float x) {
  float e = __builtin_amdgcn_exp2f(-1.44269504089f * x);
  return __builtin_amdgcn_rcpf(1.0f + e);
}
__device__ __forceinline__ float tanh_(float x) {
  float ax = __builtin_fabsf(x);
  float e = __builtin_amdgcn_exp2f(-2.88539008178f * ax);
  float t = (1.0f - e) * __builtin_amdgcn_rcpf(1.0f + e);
  return __builtin_copysignf(t, x);
}

// ---------------- setup: pre-swizzle weights into MFMA B-fragment order ----------------
// wstream: 8 waves x 8 ntiles x 9 ktiles fragments, each fragment = 64 lanes * 8 bf16 (1KB)
//   wave w handles units u0=w*32; ntile nt: gate base gb=(nt>>1)*256 + w*32 + (nt&1)*16
//   B[k][col]: lane l holds col = gb + (l&15), k = kt*32 + (l>>4)*8 + j   (j=0..7)
//   combined K: k<256 -> W_hh[g][k]; 256..263 -> W_ih[g][k-256] (x); 264 -> W_ih[g][8] (prev); else 0
// w1stream: 8 waves x 8 ktiles fragments for W1 (h2 tile w: cols w*16..w*16+16)
__global__ void prep_kernel(const float* __restrict__ W_ih, const float* __restrict__ W_hh,
                            const float* __restrict__ b_ih, const float* __restrict__ b_hh,
                            const float* __restrict__ W1,
                            unsigned short* __restrict__ wstream,
                            unsigned short* __restrict__ w1stream,
                            float* __restrict__ bias) {
  int tid = blockIdx.x * 256 + threadIdx.x;
  if (tid < 36864) {                      // 576 fragments * 64 lanes
    int f = tid >> 6, l = tid & 63;
    int w = f / 72, rem = f % 72, nt = rem / 9, kt = rem % 9;
    int g = (nt >> 1) * 256 + w * 32 + (nt & 1) * 16 + (l & 15);
    int k0 = kt * 32 + (l >> 4) * 8;
    unsigned short* dst = wstream + (size_t)f * 512 + l * 8;
#pragma unroll
    for (int j = 0; j < 8; j++) {
      int k = k0 + j;
      float v;
      if (k < 256)       v = W_hh[g * 256 + k];
      else if (k < 265)  v = W_ih[g * 9 + (k - 256)];
      else               v = 0.0f;
      dst[j] = f2bf(v);
    }
  } else if (tid < 36864 + 4096) {        // 64 fragments * 64 lanes for W1
    int t2 = tid - 36864;
    int f = t2 >> 6, l = t2 & 63;
    int w = f >> 3, kt = f & 7;
    int h2 = w * 16 + (l & 15);
    int k0 = kt * 32 + (l >> 4) * 8;
    unsigned short* dst = w1stream + (size_t)f * 512 + l * 8;
#pragma unroll
    for (int j = 0; j < 8; j++) dst[j] = f2bf(W1[h2 * 256 + k0 + j]);
  } else if (tid < 36864 + 4096 + 1024) {
    int g = tid - 36864 - 4096;
    bias[g] = b_ih[g] + b_hh[g];
  }
}

// ---------------- main persistent kernel: 16 WGs x 512 threads, 16 samples each ----------------
__global__ __launch_bounds__(512, 2) void lstm_main(
    const float* __restrict__ x, const float* __restrict__ b1,
    const float* __restrict__ W2, const float* __restrict__ b2,
    const unsigned short* __restrict__ wstream, const unsigned short* __restrict__ w1stream,
    const float* __restrict__ bias,
    float* __restrict__ out0, float* __restrict__ out1) {
  // h double-buffer: [buf][sample 16][K=288 padded to 296 bf16]  (cols 0..255 h, 256..263 x, 264 prev, 265+ zero)
  __shared__ unsigned short hlds[2][16][296];
  __shared__ unsigned short rlds[16][136];   // relu(h@W1^T+b1) bf16, padded stride
  __shared__ float w2l[128];

  const int tid = threadIdx.x;
  const int w = tid >> 6;        // wave 0..7
  const int l = tid & 63;        // lane
  const int lr = l & 15;         // tile row/col index
  const int lg = l >> 4;         // lane group 0..3
  const int n0 = blockIdx.x * 16;

  // zero h buffers (incl. zero-pad cols), stage W2
  for (int i = tid; i < 2 * 16 * 296; i += 512) ((unsigned short*)hlds)[i] = 0;
  if (tid < 128) w2l[tid] = W2[tid];
  if (tid < 16) {  // x at t=0
    const float* xp = x + (size_t)(n0 + tid) * LSEQ * 8;
#pragma unroll
    for (int j = 0; j < 8; j++) hlds[0][tid][256 + j] = f2bf(xp[j]);
  }

  // per-lane preloads
  float biasv[8];
#pragma unroll
  for (int nt = 0; nt < 8; nt++)
    biasv[nt] = bias[(nt >> 1) * 256 + w * 32 + (nt & 1) * 16 + lr];
  float b1v = b1[w * 16 + lr];
  float b2v = b2[0];
  float csub[2][4] = {{0.f, 0.f, 0.f, 0.f}, {0.f, 0.f, 0.f, 0.f}};
  const short8* wp = (const short8*)wstream;
  const short8* w1p = (const short8*)w1stream;

  __syncthreads();

  for (int t = 0; t < LSEQ; t++) {
    const int cur = t & 1, nxt = cur ^ 1;

    // ---- phase A: gates = [h|x|prev] @ Wcat^T + bias, MFMA 16x16x32, 8 ntiles x 9 ktiles ----
    short8 afr[9];
#pragma unroll
    for (int kt = 0; kt < 9; kt++)
      afr[kt] = *(const short8*)&hlds[cur][lr][kt * 32 + lg * 8];
    f32x4 acc[8];
#pragma unroll
    for (int nt = 0; nt < 8; nt++)
      acc[nt] = (f32x4){biasv[nt], biasv[nt], biasv[nt], biasv[nt]};
#pragma unroll
    for (int nt = 0; nt < 8; nt++) {
#pragma unroll
      for (int kt = 0; kt < 9; kt++) {
        short8 bfr = wp[(size_t)((w * 8 + nt) * 9 + kt) * 64 + l];
        acc[nt] = __builtin_amdgcn_mfma_f32_16x16x32_bf16(afr[kt], bfr, acc[nt], 0, 0, 0);
      }
    }

    // ---- activations + cell update (fully in-register; lane owns unit u, 4 samples, 2 subtiles) ----
#pragma unroll
    for (int j = 0; j < 2; j++) {
      const int u = w * 32 + j * 16 + lr;
#pragma unroll
      for (int r = 0; r < 4; r++) {
        float iv = sigm(acc[0 + j][r]);
        float fv = sigm(acc[2 + j][r]);
        float gv = tanh_(acc[4 + j][r]);
        float ov = sigm(acc[6 + j][r]);
        float c = fv * csub[j][r] + iv * gv;
        csub[j][r] = c;
        float h = ov * tanh_(c);
        hlds[nxt][lg * 4 + r][u] = f2bf(h);
        __builtin_nontemporal_store(c, out1 + ((size_t)(n0 + lg * 4 + r) * LSEQ + t) * 256 + u);
      }
    }
    __syncthreads();   // new h complete

    // ---- phase B: MLP layer 1, wave w computes h2 tile w (16 cols), K=256 ----
    {
      short8 a2[8];
#pragma unroll
      for (int kt = 0; kt < 8; kt++)
        a2[kt] = *(const short8*)&hlds[nxt][lr][kt * 32 + lg * 8];
      f32x4 m = (f32x4){b1v, b1v, b1v, b1v};
#pragma unroll
      for (int kt = 0; kt < 8; kt++) {
        short8 bfr = w1p[(size_t)(w * 8 + kt) * 64 + l];
        m = __builtin_amdgcn_mfma_f32_16x16x32_bf16(a2[kt], bfr, m, 0, 0, 0);
      }
#pragma unroll
      for (int r = 0; r < 4; r++) {
        float v = m[r];
        v = v > 0.f ? v : 0.f;
        rlds[lg * 4 + r][w * 16 + lr] = f2bf(v);
      }
    }
    __syncthreads();   // rlds ready

    // ---- phase C: layer 2 (wave 0) + x prefetch for t+1 (wave 1) ----
    if (w == 0) {
      float s = 0.f;
#pragma unroll
      for (int c4 = 0; c4 < 4; c4++) {
        short8 rv = *(const short8*)&rlds[lr][lg * 32 + c4 * 8];
#pragma unroll
        for (int j = 0; j < 8; j++)
          s += bf2f((unsigned short)rv[j]) * w2l[lg * 32 + c4 * 8 + j];
      }
      s += __shfl_xor(s, 16, 64);
      s += __shfl_xor(s, 32, 64);
      if (l < 16) {
        float o = s + b2v;
        __builtin_nontemporal_store(o, out0 + (size_t)(n0 + lr) * LSEQ + t);
        if (t + 1 < LSEQ) hlds[nxt][lr][264] = f2bf(o);   // prev_output for t+1
      }
    } else if (w == 1 && l < 16 && t + 1 < LSEQ) {
      const float* xp = x + ((size_t)(n0 + l) * LSEQ + (t + 1)) * 8;
#pragma unroll
      for (int j = 0; j < 8; j++) hlds[nxt][l][256 + j] = f2bf(xp[j]);
    }
    __syncthreads();   // next-step inputs ready
  }
}

extern "C" void kernel_launch(void* const* d_in, const int* in_sizes, int n_in,
                              void* d_out, int out_size, void* d_ws, size_t ws_size,
                              hipStream_t stream) {
  const float* x    = (const float*)d_in[0];
  const float* W_ih = (const float*)d_in[1];
  const float* W_hh = (const float*)d_in[2];
  const float* b_ih = (const float*)d_in[3];
  const float* b_hh = (const float*)d_in[4];
  const float* W1   = (const float*)d_in[5];
  const float* b1   = (const float*)d_in[6];
  const float* W2   = (const float*)d_in[7];
  const float* b2   = (const float*)d_in[8];

  unsigned short* wstream  = (unsigned short*)d_ws;                          // 576*512 u16 = 1179648 B
  unsigned short* w1stream = (unsigned short*)((char*)d_ws + 1179648);       // 64*512 u16  = 65536 B
  float*          bias     = (float*)((char*)d_ws + 1179648 + 65536);        // 4096 B

  float* out0 = (float*)d_out;            // [256,2048,1]
  float* out1 = out0 + 256 * LSEQ;        // [256,2048,256]

  prep_kernel<<<164, 256, 0, stream>>>(W_ih, W_hh, b_ih, b_hh, W1, wstream, w1stream, bias);
  lstm_main<<<16, 512, 0, stream>>>(x, b1, W2, b2, wstream, w1stream, bias, out0, out1);
}

// Round 2
// 21733.731 us; speedup vs baseline: 1.0398x; 1.0398x over previous
//
#include <hip/hip_runtime.h>

// LSTM: N=256, L=2048, IN=8, H1=256, H2=128, OUT=1
// Strategy: 128 WGs = 16 batch-groups x 8 unit-slices. Each WG owns 32 hidden
// units; weights persistent in REGISTERS (17KB/wave). One cross-WG h-exchange
// per step via LLC packets + flags. MLP computed redundantly per WG (W1 in regs)
// so only one sync point per step.

typedef __attribute__((ext_vector_type(8))) short short8;
typedef __attribute__((ext_vector_type(4))) float f32x4;

#define LSEQ 2048
#define NGRP 16
#define NSL  8
#define MM   16

__device__ __forceinline__ unsigned short f2bf(float f) {
  unsigned int u = __float_as_uint(f);
  unsigned int r = (u + 0x7FFFu + ((u >> 16) & 1u)) >> 16;
  return (unsigned short)r;
}
__device__ __forceinline__ float sigm(float x) {
  float e = __builtin_amdgcn_exp2f(-1.44269504089f * x);
  return __builtin_amdgcn_rcpf(1.0f + e);
}
__device__ __forceinline__ float tanh_(float x) {
  float ax = __builtin_fabsf(x);
  float e = __builtin_amdgcn_exp2f(-2.88539008178f * ax);
  float t = (1.0f - e) * __builtin_amdgcn_rcpf(1.0f + e);
  return __builtin_copysignf(t, x);
}

// ---------------- setup: pre-swizzle weights into MFMA B-fragment order + zero flags ----------------
// wstream frag f = (slice*8 + nt)*9 + kt; within a slice, nt = (gate<<1)|half covers
// units [slice*32 .. +32). Lane l: col = gate*256 + slice*32 + half*16 + (l&15),
// k = kt*32 + (l>>4)*8 + j.  k<256 -> W_hh, 256..263 -> x cols of W_ih, 264 -> prev col.
__global__ void prep_kernel(const float* __restrict__ W_ih, const float* __restrict__ W_hh,
                            const float* __restrict__ b_ih, const float* __restrict__ b_hh,
                            const float* __restrict__ W1,
                            unsigned short* __restrict__ wstream,
                            unsigned short* __restrict__ w1stream,
                            float* __restrict__ bias,
                            unsigned int* __restrict__ flags) {
  int tid = blockIdx.x * 256 + threadIdx.x;
  if (tid < 36864) {                      // 576 fragments * 64 lanes
    int f = tid >> 6, l = tid & 63;
    int w = f / 72, rem = f % 72, nt = rem / 9, kt = rem % 9;
    int g = (nt >> 1) * 256 + w * 32 + (nt & 1) * 16 + (l & 15);
    int k0 = kt * 32 + (l >> 4) * 8;
    unsigned short* dst = wstream + (size_t)f * 512 + l * 8;
#pragma unroll
    for (int j = 0; j < 8; j++) {
      int k = k0 + j;
      float v;
      if (k < 256)       v = W_hh[g * 256 + k];
      else if (k < 265)  v = W_ih[g * 9 + (k - 256)];
      else               v = 0.0f;
      dst[j] = f2bf(v);
    }
  } else if (tid < 36864 + 4096) {        // 64 fragments for W1
    int t2 = tid - 36864;
    int f = t2 >> 6, l = t2 & 63;
    int w = f >> 3, kt = f & 7;
    int h2 = w * 16 + (l & 15);
    int k0 = kt * 32 + (l >> 4) * 8;
    unsigned short* dst = w1stream + (size_t)f * 512 + l * 8;
#pragma unroll
    for (int j = 0; j < 8; j++) dst[j] = f2bf(W1[h2 * 256 + k0 + j]);
  } else if (tid < 36864 + 4096 + 1024) {
    int g = tid - 36864 - 4096;
    bias[g] = b_ih[g] + b_hh[g];
  } else if (tid < 36864 + 4096 + 1024 + 512) {
    flags[tid - 36864 - 4096 - 1024] = 0u;  // NGRP*32 = 512 dwords
  }
}

// ---------------- main: 128 WGs x 512 threads ----------------
__global__ __launch_bounds__(512, 2) void lstm_main(
    const float* __restrict__ x, const float* __restrict__ b1,
    const float* __restrict__ W2, const float* __restrict__ b2,
    const unsigned short* __restrict__ wstream, const unsigned short* __restrict__ w1stream,
    const float* __restrict__ bias,
    unsigned short* __restrict__ packets, unsigned int* __restrict__ flags,
    float* __restrict__ out0, float* __restrict__ out1) {
  // A: [slot][sample][K] bf16; K: 0..255 h, 256..263 x, 264 prev, 265..287 zero, stride 296
  __shared__ unsigned short A[2][MM][296];
  __shared__ float gbuf[4][MM][35];        // [gate][sample][unit 0..31], padded
  __shared__ unsigned short hout[MM][40];  // new h slice bf16, row stride 80B (16B-aligned)
  __shared__ float part[8][17];            // layer-2 partials per wave per sample

  const int tid = threadIdx.x;
  const int w  = tid >> 6;       // wave 0..7
  const int l  = tid & 63;
  const int lr = l & 15;
  const int lg = l >> 4;
  const int bg = blockIdx.x & 15;          // batch group (same XCD for all slices)
  const int sl = blockIdx.x >> 4;          // unit slice 0..7
  const int n0 = bg * MM;
  const int u0 = sl * 32;
  const int cs = tid >> 5, cu = tid & 31;  // cell-update mapping: sample, unit

  // persistent weights in registers: 9 gate frags + 8 W1 frags per wave (68 VGPRs)
  short8 wg_[9], w1_[8];
  {
    const short8* wp  = (const short8*)wstream;
    const short8* w1p = (const short8*)w1stream;
#pragma unroll
    for (int kt = 0; kt < 9; kt++) wg_[kt] = wp[(size_t)((sl * 8 + w) * 9 + kt) * 64 + l];
#pragma unroll
    for (int kt = 0; kt < 8; kt++) w1_[kt] = w1p[(size_t)(w * 8 + kt) * 64 + l];
  }
  const float biasv = bias[(w >> 1) * 256 + u0 + (w & 1) * 16 + lr];
  const float b1v = b1[w * 16 + lr];
  const float w2v = W2[w * 16 + lr];
  const float b2v = b2[0];

  for (int i = tid; i < 2 * MM * 296; i += 512) ((unsigned short*)A)[i] = 0;

  float c_reg = 0.0f;
  unsigned int* myflags = flags + bg * 32;

  __syncthreads();

  for (int k = 0; k <= LSEQ; k++) {
    const int slot = k & 1;

    // x prefetch for this step (issued before spin to hide LLC latency)
    f32x4 xv = {0.f, 0.f, 0.f, 0.f};
    if (w == 1 && l < 32 && k < LSEQ) {
      const f32x4* xp = (const f32x4*)(x + ((size_t)(n0 + (l >> 1)) * LSEQ + k) * 8 + (l & 1) * 4);
      xv = *xp;
    }

    if (k > 0) {
      // wave w needs only packet w: spin on its producer's flag (wave-uniform)
      while (__hip_atomic_load(&myflags[w], __ATOMIC_RELAXED, __HIP_MEMORY_SCOPE_AGENT) < (unsigned)k) {}
      __builtin_amdgcn_fence(__ATOMIC_ACQUIRE, "agent");
      const unsigned short* pk = packets + (((size_t)slot * NGRP + bg) * NSL + w) * 512;
      short8 v = *(const short8*)(pk + l * 8);
      *(short8*)&A[slot][l >> 2][w * 32 + (l & 3) * 8] = v;   // h_{k-1} cols
    }
    if (w == 1 && l < 32 && k < LSEQ) {
      unsigned short* ax = &A[slot][l >> 1][256 + (l & 1) * 4];
      ax[0] = f2bf(xv.x); ax[1] = f2bf(xv.y); ax[2] = f2bf(xv.z); ax[3] = f2bf(xv.w);
    }
    __syncthreads();   // B1: h & x cols ready

    if (k > 0) {
      // MLP on h_{k-1} (full, redundant per WG): wave w -> h2 units [w*16, +16)
      f32x4 m = {b1v, b1v, b1v, b1v};
#pragma unroll
      for (int kt = 0; kt < 8; kt++) {
        short8 a2 = *(const short8*)&A[slot][lr][kt * 32 + lg * 8];
        m = __builtin_amdgcn_mfma_f32_16x16x32_bf16(a2, w1_[kt], m, 0, 0, 0);
      }
      float p[4];
#pragma unroll
      for (int r = 0; r < 4; r++) {
        float v = m[r] > 0.f ? m[r] : 0.f;
        p[r] = v * w2v;
        p[r] += __shfl_xor(p[r], 1, 64);
        p[r] += __shfl_xor(p[r], 2, 64);
        p[r] += __shfl_xor(p[r], 4, 64);
        p[r] += __shfl_xor(p[r], 8, 64);
      }
      if (lr == 0) {
#pragma unroll
        for (int r = 0; r < 4; r++) part[w][lg * 4 + r] = p[r];
      }
    }
    __syncthreads();   // B2: partials ready

    if (k > 0 && tid < MM) {
      float o = b2v;
#pragma unroll
      for (int i = 0; i < 8; i++) o += part[i][tid];
      if (sl == 0) __builtin_nontemporal_store(o, out0 + (size_t)(n0 + tid) * LSEQ + (k - 1));
      A[slot][tid][264] = f2bf(o);   // prev_output column for the gate GEMM
    }
    __syncthreads();   // B3: col 264 ready

    if (k < LSEQ) {
      // gates for this WG's 32 units: wave w = (gate w>>1, half w&1), K=288
      f32x4 acc = {biasv, biasv, biasv, biasv};
#pragma unroll
      for (int kt = 0; kt < 9; kt++) {
        short8 af = *(const short8*)&A[slot][lr][kt * 32 + lg * 8];
        acc = __builtin_amdgcn_mfma_f32_16x16x32_bf16(af, wg_[kt], acc, 0, 0, 0);
      }
#pragma unroll
      for (int r = 0; r < 4; r++) gbuf[w >> 1][lg * 4 + r][(w & 1) * 16 + lr] = acc[r];
    }
    __syncthreads();   // B4: all 4 gates in LDS

    if (k < LSEQ) {
      float iv = sigm(gbuf[0][cs][cu]);
      float fv = sigm(gbuf[1][cs][cu]);
      float gv = tanh_(gbuf[2][cs][cu]);
      float ov = sigm(gbuf[3][cs][cu]);
      float c = fv * c_reg + iv * gv;
      c_reg = c;
      float h = ov * tanh_(c);
      hout[cs][cu] = f2bf(h);
      __builtin_nontemporal_store(c, out1 + ((size_t)(n0 + cs) * LSEQ + k) * 256 + u0 + cu);
    }
    __syncthreads();   // B5: hout complete

    if (k < LSEQ && w == 0) {
      unsigned short* pk = packets + (((size_t)((k + 1) & 1) * NGRP + bg) * NSL + sl) * 512;
      short8 v = *(const short8*)&hout[l >> 2][(l & 3) * 8];
      *(short8*)(pk + l * 8) = v;
      __builtin_amdgcn_fence(__ATOMIC_RELEASE, "agent");
      if (l == 0)
        __hip_atomic_store(&myflags[sl], (unsigned)(k + 1), __ATOMIC_RELAXED, __HIP_MEMORY_SCOPE_AGENT);
    }
  }
}

extern "C" void kernel_launch(void* const* d_in, const int* in_sizes, int n_in,
                              void* d_out, int out_size, void* d_ws, size_t ws_size,
                              hipStream_t stream) {
  const float* x    = (const float*)d_in[0];
  const float* W_ih = (const float*)d_in[1];
  const float* W_hh = (const float*)d_in[2];
  const float* b_ih = (const float*)d_in[3];
  const float* b_hh = (const float*)d_in[4];
  const float* W1   = (const float*)d_in[5];
  const float* b1   = (const float*)d_in[6];
  const float* W2   = (const float*)d_in[7];
  const float* b2   = (const float*)d_in[8];

  unsigned short* wstream  = (unsigned short*)d_ws;                           // 1,179,648 B
  unsigned short* w1stream = (unsigned short*)((char*)d_ws + 1179648);        // 65,536 B
  float*          bias     = (float*)((char*)d_ws + 1179648 + 65536);         // 4,096 B
  unsigned short* packets  = (unsigned short*)((char*)d_ws + 1249280);        // 2*16*8*1024 = 262,144 B
  unsigned int*   flags    = (unsigned int*)((char*)d_ws + 1249280 + 262144); // 16*32*4 = 2,048 B

  float* out0 = (float*)d_out;            // [256,2048,1]
  float* out1 = out0 + 256 * LSEQ;        // [256,2048,256]

  prep_kernel<<<166, 256, 0, stream>>>(W_ih, W_hh, b_ih, b_hh, W1, wstream, w1stream, bias, flags);
  lstm_main<<<128, 512, 0, stream>>>(x, b1, W2, b2, wstream, w1stream, bias, packets, flags, out0, out1);
}

// Round 3
// 5524.199 us; speedup vs baseline: 4.0907x; 3.9343x over previous
//
#include <hip/hip_runtime.h>

// LSTM: N=256, L=2048, IN=8, H1=256, H2=128, OUT=1
// 128 WGs = 16 batch-groups x 8 unit-slices; weights persistent in registers.
// Cross-WG h-exchange via LLC with relaxed agent atomics (sc-coherent, NO fences).
// Raw s_barrier (no vmcnt drain) so HBM c-stores stay off the critical path.

typedef __attribute__((ext_vector_type(8))) short short8;
typedef __attribute__((ext_vector_type(4))) float f32x4;
typedef __attribute__((ext_vector_type(2))) float f32x2;

#define LSEQ 2048

__device__ __forceinline__ unsigned short f2bf(float f) {
  unsigned int u = __float_as_uint(f);
  return (unsigned short)((u + 0x7FFFu + ((u >> 16) & 1u)) >> 16);
}
__device__ __forceinline__ float sigm(float x) {
  float e = __builtin_amdgcn_exp2f(-1.44269504089f * x);
  return __builtin_amdgcn_rcpf(1.0f + e);
}
__device__ __forceinline__ float tanh_(float x) {
  float ax = __builtin_fabsf(x);
  float e = __builtin_amdgcn_exp2f(-2.88539008178f * ax);
  float t = (1.0f - e) * __builtin_amdgcn_rcpf(1.0f + e);
  return __builtin_copysignf(t, x);
}
// raw barrier: LDS ordering only -- no vmcnt drain (keeps HBM stores async)
__device__ __forceinline__ void wg_barrier() {
  __asm__ __volatile__("s_waitcnt lgkmcnt(0)" ::: "memory");
  __builtin_amdgcn_s_barrier();
}

// ---------------- setup: pre-swizzle weights (prev column ZEROED; rank-1 at use) ----------------
__global__ void prep_kernel(const float* __restrict__ W_ih, const float* __restrict__ W_hh,
                            const float* __restrict__ b_ih, const float* __restrict__ b_hh,
                            const float* __restrict__ W1,
                            unsigned short* __restrict__ wstream,
                            unsigned short* __restrict__ w1stream,
                            float* __restrict__ bias,
                            unsigned int* __restrict__ flags) {
  int tid = blockIdx.x * 256 + threadIdx.x;
  if (tid < 36864) {                      // 576 gate fragments * 64 lanes
    int f = tid >> 6, l = tid & 63;
    int w = f / 72, rem = f % 72, nt = rem / 9, kt = rem % 9;
    int g = (nt >> 1) * 256 + w * 32 + (nt & 1) * 16 + (l & 15);
    int k0 = kt * 32 + (l >> 4) * 8;
    unsigned short* dst = wstream + (size_t)f * 512 + l * 8;
#pragma unroll
    for (int j = 0; j < 8; j++) {
      int k = k0 + j;
      float v;
      if (k < 256)       v = W_hh[g * 256 + k];
      else if (k < 264)  v = W_ih[g * 9 + (k - 256)];   // x columns only
      else               v = 0.0f;                       // prev handled rank-1
      dst[j] = f2bf(v);
    }
  } else if (tid < 36864 + 4096) {        // 64 W1 fragments
    int t2 = tid - 36864;
    int f = t2 >> 6, l = t2 & 63;
    int w = f >> 3, kt = f & 7;
    int h2 = w * 16 + (l & 15);
    int k0 = kt * 32 + (l >> 4) * 8;
    unsigned short* dst = w1stream + (size_t)f * 512 + l * 8;
#pragma unroll
    for (int j = 0; j < 8; j++) dst[j] = f2bf(W1[h2 * 256 + k0 + j]);
  } else if (tid < 36864 + 4096 + 1024) {
    int g = tid - 36864 - 4096;
    bias[g] = b_ih[g] + b_hh[g];
  } else if (tid < 36864 + 4096 + 1024 + 2048) {
    flags[tid - 36864 - 4096 - 1024] = 0u;   // 16 bg * 8 sl * 16-dword spacing
  }
}

// ---------------- main: 128 WGs x 512 threads ----------------
__global__ __launch_bounds__(512, 2) void lstm_main(
    const float* __restrict__ x, const float* __restrict__ W_ih,
    const float* __restrict__ b1, const float* __restrict__ W2, const float* __restrict__ b2,
    const unsigned short* __restrict__ wstream, const unsigned short* __restrict__ w1stream,
    const float* __restrict__ bias,
    unsigned short* __restrict__ packets, unsigned int* __restrict__ flags,
    float* __restrict__ out0, float* __restrict__ out1) {
  __shared__ unsigned short A[2][16][296];   // [slot][sample][K]: 0..255 h, 256..263 x, 264.. zero
  __shared__ float gbuf[4][16][34];          // [gate][sample][unit pair-aligned]
  __shared__ unsigned short hout[16][40];    // new h slice (row 80B, 16B aligned)
  __shared__ float part[8][17];              // MLP partials
  __shared__ float olds[16];                 // out_{k-1} per sample

  const int tid = threadIdx.x;
  const int w = tid >> 6, l = tid & 63, lr = l & 15, lg = l >> 4;
  const int bg = blockIdx.x & 15, sl = blockIdx.x >> 4;
  const int n0 = bg * 16, u0 = sl * 32;

  // persistent weights in registers (17 frags = 68 VGPRs)
  short8 wg_[9], w1_[8];
  {
    const short8* wp = (const short8*)wstream;
    const short8* w1p = (const short8*)w1stream;
#pragma unroll
    for (int kt = 0; kt < 9; kt++) wg_[kt] = wp[(size_t)((sl * 8 + w) * 9 + kt) * 64 + l];
#pragma unroll
    for (int kt = 0; kt < 8; kt++) w1_[kt] = w1p[(size_t)(w * 8 + kt) * 64 + l];
  }
  const float biasv = bias[(w >> 1) * 256 + u0 + (w & 1) * 16 + lr];
  const float b1v = b1[w * 16 + lr];
  const float w2v = W2[w * 16 + lr];
  const float b2v = b2[0];

  // cell-wave (4..7) per-lane state: 2 cells (sample cs, units u0+cu2, +1)
  int cs = 0, cu2 = 0;
  float wpv[8];
  float c0r = 0.f, c1r = 0.f;
  if (w >= 4) {
    int idx = tid - 256;
    cs = idx >> 4; cu2 = (idx & 15) * 2;
#pragma unroll
    for (int g = 0; g < 4; g++) {
      wpv[g * 2 + 0] = W_ih[(g * 256 + u0 + cu2) * 9 + 8];
      wpv[g * 2 + 1] = W_ih[(g * 256 + u0 + cu2 + 1) * 9 + 8];
    }
  }

  for (int i = tid; i < 2 * 16 * 296; i += 512) ((unsigned short*)A)[i] = 0;
  if (tid < 16) olds[tid] = 0.f;

  unsigned int* fl = flags + bg * 128;          // flag for slice s at fl[s*16]
  unsigned int* ownfl = fl + sl * 16;

  __syncthreads();   // init barrier (weight loads drained once, fine)

  for (int k = 0; k <= LSEQ; k++) {
    const int slot = k & 1;

    // ---- P1: receive h_{k-1} (remote slices) + stage x_k ----
    if (w == 1 && l < 32 && k < LSEQ) {
      f32x4 xv = *(const f32x4*)(x + ((size_t)(n0 + (l >> 1)) * LSEQ + k) * 8 + (l & 1) * 4);
      unsigned short* ax = &A[slot][l >> 1][256 + (l & 1) * 4];
      ax[0] = f2bf(xv.x); ax[1] = f2bf(xv.y); ax[2] = f2bf(xv.z); ax[3] = f2bf(xv.w);
    }
    if (k > 0 && w != sl) {
      while (__hip_atomic_load(&fl[w * 16], __ATOMIC_RELAXED, __HIP_MEMORY_SCOPE_AGENT) < (unsigned)k) {}
      __asm__ __volatile__("" ::: "memory");
      const unsigned long long* pk =
          (const unsigned long long*)(packets + (((size_t)slot * 16 + bg) * 8 + w) * 512);
      unsigned long long d0 = __hip_atomic_load(&pk[l * 2],     __ATOMIC_RELAXED, __HIP_MEMORY_SCOPE_AGENT);
      unsigned long long d1 = __hip_atomic_load(&pk[l * 2 + 1], __ATOMIC_RELAXED, __HIP_MEMORY_SCOPE_AGENT);
      unsigned long long* dst = (unsigned long long*)&A[slot][l >> 2][w * 32 + (l & 3) * 8];
      dst[0] = d0; dst[1] = d1;
    }
    wg_barrier();   // B1

    // ---- P2: fused gate GEMM (k<LSEQ) + MLP for out_{k-1} (k>0) ----
    short8 afr[9];
#pragma unroll
    for (int kt = 0; kt < 9; kt++)
      afr[kt] = *(const short8*)&A[slot][lr][kt * 32 + lg * 8];
    if (k < LSEQ) {
      f32x4 acc = {biasv, biasv, biasv, biasv};
#pragma unroll
      for (int kt = 0; kt < 9; kt++)
        acc = __builtin_amdgcn_mfma_f32_16x16x32_bf16(afr[kt], wg_[kt], acc, 0, 0, 0);
#pragma unroll
      for (int r = 0; r < 4; r++) gbuf[w >> 1][lg * 4 + r][(w & 1) * 16 + lr] = acc[r];
    }
    if (k > 0) {
      f32x4 m = {b1v, b1v, b1v, b1v};
#pragma unroll
      for (int kt = 0; kt < 8; kt++)
        m = __builtin_amdgcn_mfma_f32_16x16x32_bf16(afr[kt], w1_[kt], m, 0, 0, 0);
      float p[4];
#pragma unroll
      for (int r = 0; r < 4; r++) {
        float v = m[r] > 0.f ? m[r] : 0.f;
        p[r] = v * w2v;
        p[r] += __shfl_xor(p[r], 1, 64);
        p[r] += __shfl_xor(p[r], 2, 64);
        p[r] += __shfl_xor(p[r], 4, 64);
        p[r] += __shfl_xor(p[r], 8, 64);
      }
      if (lr == 0) {
#pragma unroll
        for (int r = 0; r < 4; r++) part[w][lg * 4 + r] = p[r];
      }
    }
    wg_barrier();   // B2

    // ---- P3: out reduce (wave 3; out0 store fire-and-forget) ----
    if (k > 0 && w == 3 && l < 16) {
      float o = b2v;
#pragma unroll
      for (int i = 0; i < 8; i++) o += part[i][l];
      olds[l] = o;
      if (sl == 0) __builtin_nontemporal_store(o, out0 + (size_t)(n0 + l) * LSEQ + (k - 1));
    }
    wg_barrier();   // B3

    // ---- P4: cell update (waves 4..7), rank-1 prev add; c-store fire-and-forget ----
    if (k < LSEQ && w >= 4) {
      float o = olds[cs];
      float gi0 = gbuf[0][cs][cu2] + wpv[0] * o, gi1 = gbuf[0][cs][cu2 + 1] + wpv[1] * o;
      float gf0 = gbuf[1][cs][cu2] + wpv[2] * o, gf1 = gbuf[1][cs][cu2 + 1] + wpv[3] * o;
      float gg0 = gbuf[2][cs][cu2] + wpv[4] * o, gg1 = gbuf[2][cs][cu2 + 1] + wpv[5] * o;
      float go0 = gbuf[3][cs][cu2] + wpv[6] * o, go1 = gbuf[3][cs][cu2 + 1] + wpv[7] * o;
      c0r = sigm(gf0) * c0r + sigm(gi0) * tanh_(gg0);
      c1r = sigm(gf1) * c1r + sigm(gi1) * tanh_(gg1);
      float h0 = sigm(go0) * tanh_(c0r);
      float h1 = sigm(go1) * tanh_(c1r);
      f32x2 cv = {c0r, c1r};
      __builtin_nontemporal_store(cv, (f32x2*)(out1 + ((size_t)(n0 + cs) * LSEQ + k) * 256 + u0 + cu2));
      hout[cs][cu2] = f2bf(h0); hout[cs][cu2 + 1] = f2bf(h1);
      // own-slice h short-circuit into next A slot (no LLC round trip)
      unsigned short* an = &A[slot ^ 1][cs][u0 + cu2];
      an[0] = f2bf(h0); an[1] = f2bf(h1);
    }
    wg_barrier();   // B4

    // ---- P5: wave 0 publishes packet (only LLC stores in its vmcnt) ----
    if (k < LSEQ && w == 0) {
      short8 hv = *(const short8*)&hout[l >> 2][(l & 3) * 8];
      unsigned long long* pk =
          (unsigned long long*)(packets + (((size_t)((k + 1) & 1) * 16 + bg) * 8 + sl) * 512);
      const unsigned long long* s64 = (const unsigned long long*)&hv;
      __hip_atomic_store(&pk[l * 2],     s64[0], __ATOMIC_RELAXED, __HIP_MEMORY_SCOPE_AGENT);
      __hip_atomic_store(&pk[l * 2 + 1], s64[1], __ATOMIC_RELAXED, __HIP_MEMORY_SCOPE_AGENT);
      __asm__ __volatile__("s_waitcnt vmcnt(0)" ::: "memory");   // packet durable at LLC
      if (l == 0)
        __hip_atomic_store(ownfl, (unsigned)(k + 1), __ATOMIC_RELAXED, __HIP_MEMORY_SCOPE_AGENT);
    }
  }
}

extern "C" void kernel_launch(void* const* d_in, const int* in_sizes, int n_in,
                              void* d_out, int out_size, void* d_ws, size_t ws_size,
                              hipStream_t stream) {
  const float* x    = (const float*)d_in[0];
  const float* W_ih = (const float*)d_in[1];
  const float* W_hh = (const float*)d_in[2];
  const float* b_ih = (const float*)d_in[3];
  const float* b_hh = (const float*)d_in[4];
  const float* W1   = (const float*)d_in[5];
  const float* b1   = (const float*)d_in[6];
  const float* W2   = (const float*)d_in[7];
  const float* b2   = (const float*)d_in[8];

  unsigned short* wstream  = (unsigned short*)d_ws;                           // 1,179,648 B
  unsigned short* w1stream = (unsigned short*)((char*)d_ws + 1179648);        // 65,536 B
  float*          bias     = (float*)((char*)d_ws + 1179648 + 65536);         // 4,096 B
  unsigned short* packets  = (unsigned short*)((char*)d_ws + 1249280);        // 262,144 B
  unsigned int*   flags    = (unsigned int*)((char*)d_ws + 1249280 + 262144); // 8,192 B

  float* out0 = (float*)d_out;            // [256,2048,1]
  float* out1 = out0 + 256 * LSEQ;        // [256,2048,256]

  prep_kernel<<<172, 256, 0, stream>>>(W_ih, W_hh, b_ih, b_hh, W1, wstream, w1stream, bias, flags);
  lstm_main<<<128, 512, 0, stream>>>(x, W_ih, b1, W2, b2, wstream, w1stream, bias, packets, flags,
                                     out0, out1);
}